// Round 9
// baseline (262.999 us; speedup 1.0000x reference)
//
#include <hip/hip_runtime.h>
#include <hip/hip_bf16.h>
#include <math.h>

#define N_NODES 10000
#define N_EDGES 160000
#define BS      4
#define N_TOT   (BS * N_NODES)   // 40000 rows
#define HID     128
#define NPC     4                // nodes per aggregate block (2 waves x 2 nodes)
#define CHUNKS  (N_NODES/NPC)    // 2500
#define HID_FC  512
#define N_CLASSES 10
#define N_LAYERS  4
#define DEG_CAP 64               // padded CSR bucket (Poisson(16): max ~40)
#define ZERO_INT4 325000         // (2*10000 + 2*10000*64)/4

using bf16x8 = __attribute__((ext_vector_type(8))) short;
using f32x4  = __attribute__((ext_vector_type(4))) float;
using f32x2  = __attribute__((ext_vector_type(2))) float;

__device__ __forceinline__ unsigned bf_rne(float x) {
    unsigned b = __float_as_uint(x);
    return (b + 0x7fffu + ((b >> 16) & 1u)) >> 16;
}
__device__ __forceinline__ float bf2f(unsigned hi16) { return __uint_as_float(hi16 << 16); }

// ---------------- fp8 e4m3 helpers ----------------
#if __has_builtin(__builtin_amdgcn_cvt_pk_f32_fp8) && __has_builtin(__builtin_amdgcn_cvt_pk_fp8_f32)
#define HW_FP8 1
#else
#define HW_FP8 0
#endif

__device__ __forceinline__ float fp8_dec1(unsigned b) {
    unsigned s = (b & 0x80u) << 24;
    unsigned em = b & 0x7Fu;
    float mag;
    if (em >= 8u) mag = __uint_as_float((((em >> 3) + 120u) << 23) | ((em & 7u) << 20));
    else          mag = (float)em * 0x1p-9f;
    return __uint_as_float(s | __float_as_uint(mag));
}

__device__ __forceinline__ unsigned fp8_enc(float x) {
#if HW_FP8
    return (unsigned)(__builtin_amdgcn_cvt_pk_fp8_f32(x, x, 0, false) & 0xFF);
#else
    unsigned s = (__float_as_uint(x) >> 24) & 0x80u;
    float ax = fabsf(x);
    unsigned r;
    if (ax >= 0x1p-6f) {
        if (ax > 448.f) r = 0x7Eu;
        else {
            unsigned b = __float_as_uint(ax);
            unsigned t = b + 0x7FFFFu + ((b >> 20) & 1u);
            r = (t >> 20) - 960u;
        }
    } else {
        r = (unsigned)__float2int_rn(ax * 512.f);
    }
    return s | r;
#endif
}

// decode 8 fp8 (little-endian bytes of uint2) -> f[0..7]
__device__ __forceinline__ void fp8x8_dec(uint2 u, float* f) {
#if HW_FP8
    f32x2 p0 = __builtin_amdgcn_cvt_pk_f32_fp8((int)u.x, false);
    f32x2 p1 = __builtin_amdgcn_cvt_pk_f32_fp8((int)u.x, true);
    f32x2 p2 = __builtin_amdgcn_cvt_pk_f32_fp8((int)u.y, false);
    f32x2 p3 = __builtin_amdgcn_cvt_pk_f32_fp8((int)u.y, true);
    f[0] = p0[0]; f[1] = p0[1]; f[2] = p1[0]; f[3] = p1[1];
    f[4] = p2[0]; f[5] = p2[1]; f[6] = p3[0]; f[7] = p3[1];
#else
    f[0] = fp8_dec1(u.x & 0xFFu);         f[1] = fp8_dec1((u.x >> 8) & 0xFFu);
    f[2] = fp8_dec1((u.x >> 16) & 0xFFu); f[3] = fp8_dec1((u.x >> 24) & 0xFFu);
    f[4] = fp8_dec1(u.y & 0xFFu);         f[5] = fp8_dec1((u.y >> 8) & 0xFFu);
    f[6] = fp8_dec1((u.y >> 16) & 0xFFu); f[7] = fp8_dec1((u.y >> 24) & 0xFFu);
#endif
}

// ---------- prep: zero counts|cursor|csr + x->bf16 + transposed split weights ----------
__global__ __launch_bounds__(256) void k_prep(const float* __restrict__ x,
                                              const float* __restrict__ W1,
                                              const float* __restrict__ Ws,
                                              int4* __restrict__ zbase,
                                              ushort* __restrict__ x_bf,
                                              ushort* __restrict__ wt_hi,
                                              ushort* __restrict__ wt_lo) {
    const int gt = blockIdx.x * 256 + threadIdx.x, NT = gridDim.x * 256;
    for (int i = gt; i < ZERO_INT4; i += NT) zbase[i] = make_int4(0, 0, 0, 0);
    for (int i = gt; i < 640000; i += NT) {       // x: 2,560,000 floats as float4
        float4 v = ((const float4*)x)[i];
        ushort4 o;
        o.x = (ushort)bf_rne(v.x); o.y = (ushort)bf_rne(v.y);
        o.z = (ushort)bf_rne(v.z); o.w = (ushort)bf_rne(v.w);
        ((ushort4*)x_bf)[i] = o;
    }
    for (int i = gt; i < 57344; i += NT) {        // W^T split hi/lo
        float v;
        if (i < 8192) { int c = i >> 6, k = i & 63; v = W1[k * HID + c]; }
        else {
            int tt = i - 8192, li = tt >> 14, rem = tt & 16383;
            int c = rem >> 7, k = rem & 127;
            v = Ws[li * 16384 + k * HID + c];
        }
        unsigned hi = bf_rne(v);
        unsigned lo = bf_rne(v - bf2f(hi));
        wt_hi[i] = (ushort)hi;
        wt_lo[i] = (ushort)lo;
    }
}

__global__ void k_count(const int* __restrict__ ei, int* __restrict__ counts) {
    int e = blockIdx.x * 256 + threadIdx.x;
    if (e < N_EDGES) atomicAdd(&counts[ei[N_EDGES + e]], 1);
}

__global__ void k_fill(const int* __restrict__ ei, const int* __restrict__ counts,
                       int* __restrict__ cursor, int2* __restrict__ csr) {
    int e = blockIdx.x * 256 + threadIdx.x;
    if (e < N_EDGES) {
        int s = ei[e], d = ei[N_EDGES + e];
        float ws = rsqrtf((float)(counts[s] + 1));   // dinv[src]
        int pos = atomicAdd(&cursor[d], 1);
        if (pos < DEG_CAP)
            csr[(d << 6) + pos] = make_int2(s, __float_as_int(ws));
    }
}

// ---------- MFMA matmul: out fp8 at [n*512 + b*128 + col] (batch-interleaved rows) ----------
template<int K>
__global__ __launch_bounds__(256) void k_mm(const ushort* __restrict__ A,
                                            const ushort* __restrict__ Bt_hi,
                                            const ushort* __restrict__ Bt_lo,
                                            unsigned char* __restrict__ outF8) {
    constexpr int NS = K / 32;
    const int lane = threadIdx.x & 63;
    const int w    = threadIdx.x >> 6;
    const int row_base = blockIdx.x * 128 + w * 32;
    const int lr = lane & 15, lg = lane >> 4;

    bf16x8 a[2][NS];
    #pragma unroll
    for (int rh = 0; rh < 2; ++rh) {
        int r = row_base + rh * 16 + lr;
        if (r > N_TOT - 1) r = N_TOT - 1;
        const ushort* ap = A + (size_t)r * K + lg * 8;
        #pragma unroll
        for (int s = 0; s < NS; ++s)
            a[rh][s] = *(const bf16x8*)(ap + s * 32);
    }

    f32x4 acc[2][8];
    #pragma unroll
    for (int rh = 0; rh < 2; ++rh)
        #pragma unroll
        for (int n = 0; n < 8; ++n)
            acc[rh][n] = (f32x4){0.f, 0.f, 0.f, 0.f};

    #pragma unroll
    for (int n = 0; n < 8; ++n) {
        const ushort* bp = Bt_hi + (size_t)(n * 16 + lr) * K + lg * 8;
        const ushort* bq = Bt_lo + (size_t)(n * 16 + lr) * K + lg * 8;
        #pragma unroll
        for (int s = 0; s < NS; ++s) {
            bf16x8 bh = *(const bf16x8*)(bp + s * 32);
            bf16x8 bl = *(const bf16x8*)(bq + s * 32);
            acc[0][n] = __builtin_amdgcn_mfma_f32_16x16x32_bf16(a[0][s], bh, acc[0][n], 0, 0, 0);
            acc[1][n] = __builtin_amdgcn_mfma_f32_16x16x32_bf16(a[1][s], bh, acc[1][n], 0, 0, 0);
            acc[0][n] = __builtin_amdgcn_mfma_f32_16x16x32_bf16(a[0][s], bl, acc[0][n], 0, 0, 0);
            acc[1][n] = __builtin_amdgcn_mfma_f32_16x16x32_bf16(a[1][s], bl, acc[1][n], 0, 0, 0);
        }
    }

    // C layout: col = lane&15, row = (lane>>4)*4 + j  (m89-verified)
    #pragma unroll
    for (int rh = 0; rh < 2; ++rh) {
        int rb = row_base + rh * 16 + lg * 4;
        #pragma unroll
        for (int n = 0; n < 8; ++n) {
            int col = n * 16 + lr;
            #pragma unroll
            for (int j = 0; j < 4; ++j) {
                int r = rb + j;
                if (r < N_TOT) {
                    int b = r / N_NODES;
                    int nd = r - b * N_NODES;
                    outF8[(size_t)nd * 512 + b * 128 + col] =
                        (unsigned char)fp8_enc(acc[rh][n][j]);
                }
            }
        }
    }
}

// ---------- aggregation: batch-interleaved fp8 gather (one load serves all 4 batches) ----------
// grid 2500; block 128 = 2 waves; wave w handles nodes chunk*4 + w*2 + {0,1}.
// lane l: batch b=l>>4, channels c0=8*(l&15) .. c0+7 (8 fp8 = one uint2 gather per edge).
__global__ __launch_bounds__(128) void k_agg(const uint2* __restrict__ tmp8,
                                             const int* __restrict__ counts,
                                             const int2* __restrict__ csr,
                                             const float* __restrict__ bias,
                                             uint4* __restrict__ hA,
                                             float* __restrict__ partial) {
    const int chunk = blockIdx.x;
    const int w = threadIdx.x >> 6, l = threadIdx.x & 63;
    const int b = l >> 4, c0 = (l & 15) * 8;
    float bvv[8];
    {
        float4 b0 = *(const float4*)(bias + c0);
        float4 b1 = *(const float4*)(bias + c0 + 4);
        bvv[0] = b0.x; bvv[1] = b0.y; bvv[2] = b0.z; bvv[3] = b0.w;
        bvv[4] = b1.x; bvv[5] = b1.y; bvv[6] = b1.z; bvv[7] = b1.w;
    }
    float pool[8];
    #pragma unroll
    for (int j = 0; j < 8; ++j) pool[j] = 0.f;

    const int n0 = chunk * NPC + w * (NPC / 2);
    for (int n = n0; n < n0 + NPC / 2; ++n) {
        int cnt = counts[n];
        const float dn = rsqrtf((float)(cnt + 1));
        if (cnt > DEG_CAP) cnt = DEG_CAP;
        const int no = (cnt + 7) >> 3;          // octets (padding entries are zero)
        float acc[8];
        {
            uint2 us = tmp8[n * 64 + l];
            float sf[8];
            fp8x8_dec(us, sf);
            #pragma unroll
            for (int j = 0; j < 8; ++j) acc[j] = dn * sf[j];   // self (x dn again at end)
        }
        const int4* cp = (const int4*)(csr + ((size_t)n << 6));
        for (int q = 0; q < no; ++q) {
            int4 q0 = cp[4 * q], q1 = cp[4 * q + 1], q2 = cp[4 * q + 2], q3 = cp[4 * q + 3];
            uint2 u0 = tmp8[q0.x * 64 + l];
            uint2 u1 = tmp8[q0.z * 64 + l];
            uint2 u2 = tmp8[q1.x * 64 + l];
            uint2 u3 = tmp8[q1.z * 64 + l];
            uint2 u4 = tmp8[q2.x * 64 + l];
            uint2 u5 = tmp8[q2.z * 64 + l];
            uint2 u6 = tmp8[q3.x * 64 + l];
            uint2 u7 = tmp8[q3.z * 64 + l];
            float w0 = __int_as_float(q0.y), w1 = __int_as_float(q0.w);
            float w2 = __int_as_float(q1.y), w3 = __int_as_float(q1.w);
            float w4 = __int_as_float(q2.y), w5 = __int_as_float(q2.w);
            float w6 = __int_as_float(q3.y), w7 = __int_as_float(q3.w);
            float f[8];
            fp8x8_dec(u0, f);
            #pragma unroll
            for (int j = 0; j < 8; ++j) acc[j] = fmaf(w0, f[j], acc[j]);
            fp8x8_dec(u1, f);
            #pragma unroll
            for (int j = 0; j < 8; ++j) acc[j] = fmaf(w1, f[j], acc[j]);
            fp8x8_dec(u2, f);
            #pragma unroll
            for (int j = 0; j < 8; ++j) acc[j] = fmaf(w2, f[j], acc[j]);
            fp8x8_dec(u3, f);
            #pragma unroll
            for (int j = 0; j < 8; ++j) acc[j] = fmaf(w3, f[j], acc[j]);
            fp8x8_dec(u4, f);
            #pragma unroll
            for (int j = 0; j < 8; ++j) acc[j] = fmaf(w4, f[j], acc[j]);
            fp8x8_dec(u5, f);
            #pragma unroll
            for (int j = 0; j < 8; ++j) acc[j] = fmaf(w5, f[j], acc[j]);
            fp8x8_dec(u6, f);
            #pragma unroll
            for (int j = 0; j < 8; ++j) acc[j] = fmaf(w6, f[j], acc[j]);
            fp8x8_dec(u7, f);
            #pragma unroll
            for (int j = 0; j < 8; ++j) acc[j] = fmaf(w7, f[j], acc[j]);
        }
        float r[8];
        #pragma unroll
        for (int j = 0; j < 8; ++j) {
            r[j] = fmaxf(fmaf(dn, acc[j], bvv[j]), 0.f);
            pool[j] += r[j];
        }
        uint4 ov;
        ov.x = bf_rne(r[0]) | (bf_rne(r[1]) << 16);
        ov.y = bf_rne(r[2]) | (bf_rne(r[3]) << 16);
        ov.z = bf_rne(r[4]) | (bf_rne(r[5]) << 16);
        ov.w = bf_rne(r[6]) | (bf_rne(r[7]) << 16);
        hA[(size_t)(b * N_NODES + n) * 16 + (c0 >> 3)] = ov;   // 16B = 8 bf16
    }

    __shared__ float pw[64][8];
    if (w == 1) {
        #pragma unroll
        for (int j = 0; j < 8; ++j) pw[l][j] = pool[j];
    }
    __syncthreads();
    if (w == 0) {
        #pragma unroll
        for (int j = 0; j < 8; ++j) pool[j] += pw[l][j];
        float* pp = partial + ((size_t)b * CHUNKS + chunk) * HID + c0;
        *(float4*)pp = make_float4(pool[0], pool[1], pool[2], pool[3]);
        *(float4*)(pp + 4) = make_float4(pool[4], pool[5], pool[6], pool[7]);
    }
}

// ---------- pool reduce: 16 blocks (layer*4+batch), 512 threads (4-way chunk split) ----------
__global__ __launch_bounds__(512) void k_reduce(const float* __restrict__ partial,
                                                float* __restrict__ pooled) {
    const int lb = blockIdx.x;
    const int c = threadIdx.x & 127, qh = threadIdx.x >> 7;
    const float* p = partial + (size_t)lb * CHUNKS * HID + c;
    float s = 0.f;
    const int e0 = qh * (CHUNKS / 4), e1 = e0 + CHUNKS / 4;
    #pragma unroll 8
    for (int ch = e0; ch < e1; ++ch) s += p[(size_t)ch * HID];
    __shared__ float sm[4][128];
    sm[qh][c] = s;
    __syncthreads();
    if (qh == 0)
        pooled[(size_t)lb * HID + c] =
            (sm[0][c] + sm[1][c] + sm[2][c] + sm[3][c]) * (1.0f / N_NODES);
}

// ---------- lin1: [4 x 512] @ [512 x 512] + relu ----------
__global__ __launch_bounds__(256) void k_lin1(const float* __restrict__ pooled,
                                              const float* __restrict__ w,
                                              const float* __restrict__ bias,
                                              float* __restrict__ h1) {
    __shared__ float pf[BS][HID_FC];
    __shared__ float red[8][32][BS];
    const int t = threadIdx.x;
    const int o0 = blockIdx.x * 32;
    for (int i = t; i < BS * HID_FC; i += 256) {
        int b = i >> 9, f = i & 511;
        int l = f & 3, cc = f >> 2;      // stack(...,-1) interleave: f = c*4 + l
        pf[b][f] = pooled[(size_t)(l * BS + b) * HID + cc];
    }
    __syncthreads();
    const int o = t & 31, kq = t >> 5;
    float acc[BS] = {0.f, 0.f, 0.f, 0.f};
    #pragma unroll 4
    for (int k = kq * 64; k < kq * 64 + 64; ++k) {
        float wv = w[(size_t)k * HID_FC + o0 + o];
        #pragma unroll
        for (int b = 0; b < BS; ++b) acc[b] = fmaf(pf[b][k], wv, acc[b]);
    }
    #pragma unroll
    for (int b = 0; b < BS; ++b) red[kq][o][b] = acc[b];
    __syncthreads();
    if (t < 128) {
        int oo = t & 31, b = t >> 5;
        float s = 0.f;
        #pragma unroll
        for (int q = 0; q < 8; ++q) s += red[q][oo][b];
        s += bias[o0 + oo];
        h1[(size_t)b * HID_FC + o0 + oo] = fmaxf(s, 0.f);
    }
}

// ---------- lin2 + log_softmax: k-parallel, shuffle reduce ----------
__global__ __launch_bounds__(512) void k_lin2(const float* __restrict__ h1,
                                              const float* __restrict__ w,
                                              const float* __restrict__ bias,
                                              float* __restrict__ out) {
    const int k = threadIdx.x;
    const int lane = k & 63, wv_id = k >> 6;
    float wrow[N_CLASSES];
    #pragma unroll
    for (int c = 0; c < N_CLASSES; ++c) wrow[c] = w[k * N_CLASSES + c];
    float hv[BS];
    #pragma unroll
    for (int b = 0; b < BS; ++b) hv[b] = h1[b * HID_FC + k];
    float acc[BS][N_CLASSES];
    #pragma unroll
    for (int b = 0; b < BS; ++b)
        #pragma unroll
        for (int c = 0; c < N_CLASSES; ++c) acc[b][c] = hv[b] * wrow[c];
    #pragma unroll
    for (int off = 32; off >= 1; off >>= 1) {
        #pragma unroll
        for (int b = 0; b < BS; ++b)
            #pragma unroll
            for (int c = 0; c < N_CLASSES; ++c)
                acc[b][c] += __shfl_down(acc[b][c], off);
    }
    __shared__ float red[8][BS * N_CLASSES];
    if (lane == 0) {
        #pragma unroll
        for (int b = 0; b < BS; ++b)
            #pragma unroll
            for (int c = 0; c < N_CLASSES; ++c)
                red[wv_id][b * N_CLASSES + c] = acc[b][c];
    }
    __syncthreads();
    __shared__ float logits[BS][N_CLASSES];
    if (k < BS * N_CLASSES) {
        int b = k / N_CLASSES, c = k % N_CLASSES;
        float s = bias[c];
        #pragma unroll
        for (int q = 0; q < 8; ++q) s += red[q][k];
        logits[b][c] = s;
    }
    __syncthreads();
    if (k < BS) {
        float m = logits[k][0];
        for (int i = 1; i < N_CLASSES; ++i) m = fmaxf(m, logits[k][i]);
        float s = 0.f;
        for (int i = 0; i < N_CLASSES; ++i) s += expf(logits[k][i] - m);
        float lse = m + logf(s);
        for (int i = 0; i < N_CLASSES; ++i) out[k * N_CLASSES + i] = logits[k][i] - lse;
    }
}

// ---------- launch ----------
extern "C" void kernel_launch(void* const* d_in, const int* in_sizes, int n_in,
                              void* d_out, int out_size, void* d_ws, size_t ws_size,
                              hipStream_t stream) {
    const float* x       = (const float*)d_in[0];
    const int*   ei      = (const int*)d_in[1];
    const float* W1      = (const float*)d_in[3];
    const float* b1      = (const float*)d_in[4];
    const float* Ws      = (const float*)d_in[5];
    const float* bconvs  = (const float*)d_in[6];
    const float* lin1_w  = (const float*)d_in[7];
    const float* lin1_b  = (const float*)d_in[8];
    const float* lin2_w  = (const float*)d_in[9];
    const float* lin2_b  = (const float*)d_in[10];
    float* out = (float*)d_out;

    // workspace layout (all 16B aligned)
    char* base = (char*)d_ws;
    unsigned char* tmp8 = (unsigned char*)base; base += (size_t)N_NODES * 512;  // 5.12 MB interleaved
    ushort* hA16   = (ushort*)base;    base += (size_t)N_TOT * HID * 2;         // 10.24 MB
    ushort* x_bf   = (ushort*)base;    base += (size_t)N_TOT * 64 * 2;          // 5.12 MB
    ushort* wt_hi  = (ushort*)base;    base += 57344 * 2;
    ushort* wt_lo  = (ushort*)base;    base += 57344 * 2;
    float*  partial= (float*)base;     base += (size_t)N_LAYERS * BS * CHUNKS * HID * 4; // 20.5 MB
    float*  pooled = (float*)base;     base += N_LAYERS * BS * HID * 4;
    float*  h1     = (float*)base;     base += BS * HID_FC * 4;
    // contiguous zeroed int region: counts|cursor|csr
    int*    counts = (int*)base;       base += N_NODES * 4;
    int*    cursor = (int*)base;       base += N_NODES * 4;
    int2*   csr    = (int2*)base;      // 10000*64 int2 = 5.12 MB

    const int GE = (N_EDGES + 255) / 256;   // 625

    k_prep<<<1024, 256, 0, stream>>>(x, W1, Ws, (int4*)counts, x_bf, wt_hi, wt_lo);
    k_count<<<GE, 256, 0, stream>>>(ei, counts);
    k_fill<<<GE, 256, 0, stream>>>(ei, counts, cursor, csr);

    const int agg_grid = CHUNKS;                 // 2500
    const int mm_grid = (N_TOT + 127) / 128;     // 313

    k_mm<64><<<mm_grid, 256, 0, stream>>>(x_bf, wt_hi, wt_lo, tmp8);
    k_agg<<<agg_grid, 128, 0, stream>>>((const uint2*)tmp8, counts, csr, b1,
                                        (uint4*)hA16, partial);
    for (int l = 1; l < N_LAYERS; ++l) {
        const ushort* whi = wt_hi + 8192 + (size_t)(l - 1) * 16384;
        const ushort* wlo = wt_lo + 8192 + (size_t)(l - 1) * 16384;
        const float* bl = bconvs + (size_t)(l - 1) * HID;
        k_mm<128><<<mm_grid, 256, 0, stream>>>(hA16, whi, wlo, tmp8);
        k_agg<<<agg_grid, 128, 0, stream>>>((const uint2*)tmp8, counts, csr, bl,
                                            (uint4*)hA16,
                                            partial + (size_t)l * BS * CHUNKS * HID);
    }

    k_reduce<<<N_LAYERS * BS, 512, 0, stream>>>(partial, pooled);
    k_lin1<<<HID_FC / 32, 256, 0, stream>>>(pooled, lin1_w, lin1_b, h1);
    k_lin2<<<1, 512, 0, stream>>>(h1, lin2_w, lin2_b, out);
}

// Round 10
// 237.268 us; speedup vs baseline: 1.1084x; 1.1084x over previous
//
#include <hip/hip_runtime.h>
#include <hip/hip_bf16.h>
#include <math.h>

#define N_NODES 10000
#define N_EDGES 160000
#define BS      4
#define N_TOT   (BS * N_NODES)   // 40000 rows
#define HID     128
#define NPC     4                // nodes per aggregate block (2 waves x 2 nodes)
#define CHUNKS  (N_NODES/NPC)    // 2500
#define HID_FC  512
#define N_CLASSES 10
#define N_LAYERS  4
#define DEG_CAP 64               // padded CSR bucket (Poisson(16): max ~40)
#define ZERO_INT4 325000         // (2*10000 + 2*10000*64)/4
#define RED_SPLIT 32
#define RED_PER   ((CHUNKS + RED_SPLIT - 1) / RED_SPLIT)   // 79

using bf16x8 = __attribute__((ext_vector_type(8))) short;
using f32x4  = __attribute__((ext_vector_type(4))) float;
using f32x2  = __attribute__((ext_vector_type(2))) float;

__device__ __forceinline__ unsigned bf_rne(float x) {
    unsigned b = __float_as_uint(x);
    return (b + 0x7fffu + ((b >> 16) & 1u)) >> 16;
}
__device__ __forceinline__ float bf2f(unsigned hi16) { return __uint_as_float(hi16 << 16); }

// ---------------- fp8 e4m3 helpers ----------------
#if __has_builtin(__builtin_amdgcn_cvt_pk_f32_fp8) && __has_builtin(__builtin_amdgcn_cvt_pk_fp8_f32)
#define HW_FP8 1
#else
#define HW_FP8 0
#endif

__device__ __forceinline__ float fp8_dec1(unsigned b) {
    unsigned s = (b & 0x80u) << 24;
    unsigned em = b & 0x7Fu;
    float mag;
    if (em >= 8u) mag = __uint_as_float((((em >> 3) + 120u) << 23) | ((em & 7u) << 20));
    else          mag = (float)em * 0x1p-9f;
    return __uint_as_float(s | __float_as_uint(mag));
}

__device__ __forceinline__ unsigned fp8_enc(float x) {
#if HW_FP8
    return (unsigned)(__builtin_amdgcn_cvt_pk_fp8_f32(x, x, 0, false) & 0xFF);
#else
    unsigned s = (__float_as_uint(x) >> 24) & 0x80u;
    float ax = fabsf(x);
    unsigned r;
    if (ax >= 0x1p-6f) {
        if (ax > 448.f) r = 0x7Eu;
        else {
            unsigned b = __float_as_uint(ax);
            unsigned t = b + 0x7FFFFu + ((b >> 20) & 1u);
            r = (t >> 20) - 960u;
        }
    } else {
        r = (unsigned)__float2int_rn(ax * 512.f);
    }
    return s | r;
#endif
}

// decode 8 fp8 (little-endian bytes of uint2) -> f[0..7]
__device__ __forceinline__ void fp8x8_dec(uint2 u, float* f) {
#if HW_FP8
    f32x2 p0 = __builtin_amdgcn_cvt_pk_f32_fp8((int)u.x, false);
    f32x2 p1 = __builtin_amdgcn_cvt_pk_f32_fp8((int)u.x, true);
    f32x2 p2 = __builtin_amdgcn_cvt_pk_f32_fp8((int)u.y, false);
    f32x2 p3 = __builtin_amdgcn_cvt_pk_f32_fp8((int)u.y, true);
    f[0] = p0[0]; f[1] = p0[1]; f[2] = p1[0]; f[3] = p1[1];
    f[4] = p2[0]; f[5] = p2[1]; f[6] = p3[0]; f[7] = p3[1];
#else
    f[0] = fp8_dec1(u.x & 0xFFu);         f[1] = fp8_dec1((u.x >> 8) & 0xFFu);
    f[2] = fp8_dec1((u.x >> 16) & 0xFFu); f[3] = fp8_dec1((u.x >> 24) & 0xFFu);
    f[4] = fp8_dec1(u.y & 0xFFu);         f[5] = fp8_dec1((u.y >> 8) & 0xFFu);
    f[6] = fp8_dec1((u.y >> 16) & 0xFFu); f[7] = fp8_dec1((u.y >> 24) & 0xFFu);
#endif
}

// ---------- prep: zero counts|cursor|csr + x->bf16 + transposed split weights ----------
__global__ __launch_bounds__(256) void k_prep(const float* __restrict__ x,
                                              const float* __restrict__ W1,
                                              const float* __restrict__ Ws,
                                              int4* __restrict__ zbase,
                                              ushort* __restrict__ x_bf,
                                              ushort* __restrict__ wt_hi,
                                              ushort* __restrict__ wt_lo) {
    const int gt = blockIdx.x * 256 + threadIdx.x, NT = gridDim.x * 256;
    for (int i = gt; i < ZERO_INT4; i += NT) zbase[i] = make_int4(0, 0, 0, 0);
    for (int i = gt; i < 640000; i += NT) {       // x: 2,560,000 floats as float4
        float4 v = ((const float4*)x)[i];
        ushort4 o;
        o.x = (ushort)bf_rne(v.x); o.y = (ushort)bf_rne(v.y);
        o.z = (ushort)bf_rne(v.z); o.w = (ushort)bf_rne(v.w);
        ((ushort4*)x_bf)[i] = o;
    }
    for (int i = gt; i < 57344; i += NT) {        // W^T split hi/lo
        float v;
        if (i < 8192) { int c = i >> 6, k = i & 63; v = W1[k * HID + c]; }
        else {
            int tt = i - 8192, li = tt >> 14, rem = tt & 16383;
            int c = rem >> 7, k = rem & 127;
            v = Ws[li * 16384 + k * HID + c];
        }
        unsigned hi = bf_rne(v);
        unsigned lo = bf_rne(v - bf2f(hi));
        wt_hi[i] = (ushort)hi;
        wt_lo[i] = (ushort)lo;
    }
}

__global__ void k_count(const int* __restrict__ ei, int* __restrict__ counts) {
    int e = blockIdx.x * 256 + threadIdx.x;
    if (e < N_EDGES) atomicAdd(&counts[ei[N_EDGES + e]], 1);
}

__global__ void k_fill(const int* __restrict__ ei, const int* __restrict__ counts,
                       int* __restrict__ cursor, int2* __restrict__ csr) {
    int e = blockIdx.x * 256 + threadIdx.x;
    if (e < N_EDGES) {
        int s = ei[e], d = ei[N_EDGES + e];
        float ws = rsqrtf((float)(counts[s] + 1));   // dinv[src]
        int pos = atomicAdd(&cursor[d], 1);
        if (pos < DEG_CAP)
            csr[(d << 6) + pos] = make_int2(s, __float_as_int(ws));
    }
}

// ---------- MFMA matmul: out fp8 at [n*512 + b*128 + col] (batch-interleaved rows) ----------
template<int K>
__global__ __launch_bounds__(256) void k_mm(const ushort* __restrict__ A,
                                            const ushort* __restrict__ Bt_hi,
                                            const ushort* __restrict__ Bt_lo,
                                            unsigned char* __restrict__ outF8) {
    constexpr int NS = K / 32;
    const int lane = threadIdx.x & 63;
    const int w    = threadIdx.x >> 6;
    const int row_base = blockIdx.x * 128 + w * 32;
    const int lr = lane & 15, lg = lane >> 4;

    bf16x8 a[2][NS];
    #pragma unroll
    for (int rh = 0; rh < 2; ++rh) {
        int r = row_base + rh * 16 + lr;
        if (r > N_TOT - 1) r = N_TOT - 1;
        const ushort* ap = A + (size_t)r * K + lg * 8;
        #pragma unroll
        for (int s = 0; s < NS; ++s)
            a[rh][s] = *(const bf16x8*)(ap + s * 32);
    }

    f32x4 acc[2][8];
    #pragma unroll
    for (int rh = 0; rh < 2; ++rh)
        #pragma unroll
        for (int n = 0; n < 8; ++n)
            acc[rh][n] = (f32x4){0.f, 0.f, 0.f, 0.f};

    #pragma unroll
    for (int n = 0; n < 8; ++n) {
        const ushort* bp = Bt_hi + (size_t)(n * 16 + lr) * K + lg * 8;
        const ushort* bq = Bt_lo + (size_t)(n * 16 + lr) * K + lg * 8;
        #pragma unroll
        for (int s = 0; s < NS; ++s) {
            bf16x8 bh = *(const bf16x8*)(bp + s * 32);
            bf16x8 bl = *(const bf16x8*)(bq + s * 32);
            acc[0][n] = __builtin_amdgcn_mfma_f32_16x16x32_bf16(a[0][s], bh, acc[0][n], 0, 0, 0);
            acc[1][n] = __builtin_amdgcn_mfma_f32_16x16x32_bf16(a[1][s], bh, acc[1][n], 0, 0, 0);
            acc[0][n] = __builtin_amdgcn_mfma_f32_16x16x32_bf16(a[0][s], bl, acc[0][n], 0, 0, 0);
            acc[1][n] = __builtin_amdgcn_mfma_f32_16x16x32_bf16(a[1][s], bl, acc[1][n], 0, 0, 0);
        }
    }

    // C layout: col = lane&15, row = (lane>>4)*4 + j  (m89-verified)
    #pragma unroll
    for (int rh = 0; rh < 2; ++rh) {
        int rb = row_base + rh * 16 + lg * 4;
        #pragma unroll
        for (int n = 0; n < 8; ++n) {
            int col = n * 16 + lr;
            #pragma unroll
            for (int j = 0; j < 4; ++j) {
                int r = rb + j;
                if (r < N_TOT) {
                    int b = r / N_NODES;
                    int nd = r - b * N_NODES;
                    outF8[(size_t)nd * 512 + b * 128 + col] =
                        (unsigned char)fp8_enc(acc[rh][n][j]);
                }
            }
        }
    }
}

// ---------- aggregation: batch-interleaved fp8 gather (one load serves all 4 batches) ----------
// grid 2500; block 128 = 2 waves; wave w handles nodes chunk*4 + w*2 + {0,1}.
// lane l: batch b=l>>4, channels c0=8*(l&15) .. c0+7 (8 fp8 = one uint2 gather per edge).
__global__ __launch_bounds__(128) void k_agg(const uint2* __restrict__ tmp8,
                                             const int* __restrict__ counts,
                                             const int2* __restrict__ csr,
                                             const float* __restrict__ bias,
                                             uint4* __restrict__ hA,
                                             float* __restrict__ partial) {
    const int chunk = blockIdx.x;
    const int w = threadIdx.x >> 6, l = threadIdx.x & 63;
    const int b = l >> 4, c0 = (l & 15) * 8;
    float bvv[8];
    {
        float4 b0 = *(const float4*)(bias + c0);
        float4 b1 = *(const float4*)(bias + c0 + 4);
        bvv[0] = b0.x; bvv[1] = b0.y; bvv[2] = b0.z; bvv[3] = b0.w;
        bvv[4] = b1.x; bvv[5] = b1.y; bvv[6] = b1.z; bvv[7] = b1.w;
    }
    float pool[8];
    #pragma unroll
    for (int j = 0; j < 8; ++j) pool[j] = 0.f;

    const int n0 = chunk * NPC + w * (NPC / 2);
    for (int n = n0; n < n0 + NPC / 2; ++n) {
        int cnt = counts[n];
        const float dn = rsqrtf((float)(cnt + 1));
        if (cnt > DEG_CAP) cnt = DEG_CAP;
        const int no = (cnt + 7) >> 3;          // octets (padding entries are zero)
        float acc[8];
        {
            uint2 us = tmp8[n * 64 + l];
            float sf[8];
            fp8x8_dec(us, sf);
            #pragma unroll
            for (int j = 0; j < 8; ++j) acc[j] = dn * sf[j];   // self (x dn again at end)
        }
        const int4* cp = (const int4*)(csr + ((size_t)n << 6));
        for (int q = 0; q < no; ++q) {
            int4 q0 = cp[4 * q], q1 = cp[4 * q + 1], q2 = cp[4 * q + 2], q3 = cp[4 * q + 3];
            uint2 u0 = tmp8[q0.x * 64 + l];
            uint2 u1 = tmp8[q0.z * 64 + l];
            uint2 u2 = tmp8[q1.x * 64 + l];
            uint2 u3 = tmp8[q1.z * 64 + l];
            uint2 u4 = tmp8[q2.x * 64 + l];
            uint2 u5 = tmp8[q2.z * 64 + l];
            uint2 u6 = tmp8[q3.x * 64 + l];
            uint2 u7 = tmp8[q3.z * 64 + l];
            float w0 = __int_as_float(q0.y), w1 = __int_as_float(q0.w);
            float w2 = __int_as_float(q1.y), w3 = __int_as_float(q1.w);
            float w4 = __int_as_float(q2.y), w5 = __int_as_float(q2.w);
            float w6 = __int_as_float(q3.y), w7 = __int_as_float(q3.w);
            float f[8];
            fp8x8_dec(u0, f);
            #pragma unroll
            for (int j = 0; j < 8; ++j) acc[j] = fmaf(w0, f[j], acc[j]);
            fp8x8_dec(u1, f);
            #pragma unroll
            for (int j = 0; j < 8; ++j) acc[j] = fmaf(w1, f[j], acc[j]);
            fp8x8_dec(u2, f);
            #pragma unroll
            for (int j = 0; j < 8; ++j) acc[j] = fmaf(w2, f[j], acc[j]);
            fp8x8_dec(u3, f);
            #pragma unroll
            for (int j = 0; j < 8; ++j) acc[j] = fmaf(w3, f[j], acc[j]);
            fp8x8_dec(u4, f);
            #pragma unroll
            for (int j = 0; j < 8; ++j) acc[j] = fmaf(w4, f[j], acc[j]);
            fp8x8_dec(u5, f);
            #pragma unroll
            for (int j = 0; j < 8; ++j) acc[j] = fmaf(w5, f[j], acc[j]);
            fp8x8_dec(u6, f);
            #pragma unroll
            for (int j = 0; j < 8; ++j) acc[j] = fmaf(w6, f[j], acc[j]);
            fp8x8_dec(u7, f);
            #pragma unroll
            for (int j = 0; j < 8; ++j) acc[j] = fmaf(w7, f[j], acc[j]);
        }
        float r[8];
        #pragma unroll
        for (int j = 0; j < 8; ++j) {
            r[j] = fmaxf(fmaf(dn, acc[j], bvv[j]), 0.f);
            pool[j] += r[j];
        }
        uint4 ov;
        ov.x = bf_rne(r[0]) | (bf_rne(r[1]) << 16);
        ov.y = bf_rne(r[2]) | (bf_rne(r[3]) << 16);
        ov.z = bf_rne(r[4]) | (bf_rne(r[5]) << 16);
        ov.w = bf_rne(r[6]) | (bf_rne(r[7]) << 16);
        hA[(size_t)(b * N_NODES + n) * 16 + (c0 >> 3)] = ov;   // 16B = 8 bf16
    }

    __shared__ float pw[64][8];
    if (w == 1) {
        #pragma unroll
        for (int j = 0; j < 8; ++j) pw[l][j] = pool[j];
    }
    __syncthreads();
    if (w == 0) {
        #pragma unroll
        for (int j = 0; j < 8; ++j) pool[j] += pw[l][j];
        float* pp = partial + ((size_t)b * CHUNKS + chunk) * HID + c0;
        *(float4*)pp = make_float4(pool[0], pool[1], pool[2], pool[3]);
        *(float4*)(pp + 4) = make_float4(pool[4], pool[5], pool[6], pool[7]);
    }
}

// ---------- pool reduce stage 1: 512 blocks (16 lb x 32 sub), 128 threads ----------
__global__ __launch_bounds__(128) void k_red1(const float* __restrict__ partial,
                                              float* __restrict__ partial2) {
    const int bid = blockIdx.x;
    const int lb = bid >> 5, s = bid & 31;
    const int c = threadIdx.x;
    const int e0 = s * RED_PER;
    int e1 = e0 + RED_PER;
    if (e1 > CHUNKS) e1 = CHUNKS;
    const float* p = partial + (size_t)lb * CHUNKS * HID + c;
    float sum = 0.f;
    for (int ch = e0; ch < e1; ++ch) sum += p[(size_t)ch * HID];
    partial2[(size_t)bid * HID + c] = sum;
}

// ---------- pool reduce stage 2: 16 blocks, 128 threads ----------
__global__ __launch_bounds__(128) void k_red2(const float* __restrict__ partial2,
                                              float* __restrict__ pooled) {
    const int lb = blockIdx.x, c = threadIdx.x;
    const float* p = partial2 + (size_t)lb * 32 * HID + c;
    float s = 0.f;
    #pragma unroll
    for (int q = 0; q < 32; ++q) s += p[q * HID];
    pooled[(size_t)lb * HID + c] = s * (1.0f / N_NODES);
}

// ---------- lin1: [4 x 512] @ [512 x 512] + relu ----------
__global__ __launch_bounds__(256) void k_lin1(const float* __restrict__ pooled,
                                              const float* __restrict__ w,
                                              const float* __restrict__ bias,
                                              float* __restrict__ h1) {
    __shared__ float pf[BS][HID_FC];
    __shared__ float red[8][32][BS];
    const int t = threadIdx.x;
    const int o0 = blockIdx.x * 32;
    for (int i = t; i < BS * HID_FC; i += 256) {
        int b = i >> 9, f = i & 511;
        int l = f & 3, cc = f >> 2;      // stack(...,-1) interleave: f = c*4 + l
        pf[b][f] = pooled[(size_t)(l * BS + b) * HID + cc];
    }
    __syncthreads();
    const int o = t & 31, kq = t >> 5;
    float acc[BS] = {0.f, 0.f, 0.f, 0.f};
    #pragma unroll 4
    for (int k = kq * 64; k < kq * 64 + 64; ++k) {
        float wv = w[(size_t)k * HID_FC + o0 + o];
        #pragma unroll
        for (int b = 0; b < BS; ++b) acc[b] = fmaf(pf[b][k], wv, acc[b]);
    }
    #pragma unroll
    for (int b = 0; b < BS; ++b) red[kq][o][b] = acc[b];
    __syncthreads();
    if (t < 128) {
        int oo = t & 31, b = t >> 5;
        float s = 0.f;
        #pragma unroll
        for (int q = 0; q < 8; ++q) s += red[q][oo][b];
        s += bias[o0 + oo];
        h1[(size_t)b * HID_FC + o0 + oo] = fmaxf(s, 0.f);
    }
}

// ---------- lin2 + log_softmax: k-parallel, shuffle reduce ----------
__global__ __launch_bounds__(512) void k_lin2(const float* __restrict__ h1,
                                              const float* __restrict__ w,
                                              const float* __restrict__ bias,
                                              float* __restrict__ out) {
    const int k = threadIdx.x;
    const int lane = k & 63, wv_id = k >> 6;
    float wrow[N_CLASSES];
    #pragma unroll
    for (int c = 0; c < N_CLASSES; ++c) wrow[c] = w[k * N_CLASSES + c];
    float hv[BS];
    #pragma unroll
    for (int b = 0; b < BS; ++b) hv[b] = h1[b * HID_FC + k];
    float acc[BS][N_CLASSES];
    #pragma unroll
    for (int b = 0; b < BS; ++b)
        #pragma unroll
        for (int c = 0; c < N_CLASSES; ++c) acc[b][c] = hv[b] * wrow[c];
    #pragma unroll
    for (int off = 32; off >= 1; off >>= 1) {
        #pragma unroll
        for (int b = 0; b < BS; ++b)
            #pragma unroll
            for (int c = 0; c < N_CLASSES; ++c)
                acc[b][c] += __shfl_down(acc[b][c], off);
    }
    __shared__ float red[8][BS * N_CLASSES];
    if (lane == 0) {
        #pragma unroll
        for (int b = 0; b < BS; ++b)
            #pragma unroll
            for (int c = 0; c < N_CLASSES; ++c)
                red[wv_id][b * N_CLASSES + c] = acc[b][c];
    }
    __syncthreads();
    __shared__ float logits[BS][N_CLASSES];
    if (k < BS * N_CLASSES) {
        int b = k / N_CLASSES, c = k % N_CLASSES;
        float s = bias[c];
        #pragma unroll
        for (int q = 0; q < 8; ++q) s += red[q][k];
        logits[b][c] = s;
    }
    __syncthreads();
    if (k < BS) {
        float m = logits[k][0];
        for (int i = 1; i < N_CLASSES; ++i) m = fmaxf(m, logits[k][i]);
        float s = 0.f;
        for (int i = 0; i < N_CLASSES; ++i) s += expf(logits[k][i] - m);
        float lse = m + logf(s);
        for (int i = 0; i < N_CLASSES; ++i) out[k * N_CLASSES + i] = logits[k][i] - lse;
    }
}

// ---------- launch ----------
extern "C" void kernel_launch(void* const* d_in, const int* in_sizes, int n_in,
                              void* d_out, int out_size, void* d_ws, size_t ws_size,
                              hipStream_t stream) {
    const float* x       = (const float*)d_in[0];
    const int*   ei      = (const int*)d_in[1];
    const float* W1      = (const float*)d_in[3];
    const float* b1      = (const float*)d_in[4];
    const float* Ws      = (const float*)d_in[5];
    const float* bconvs  = (const float*)d_in[6];
    const float* lin1_w  = (const float*)d_in[7];
    const float* lin1_b  = (const float*)d_in[8];
    const float* lin2_w  = (const float*)d_in[9];
    const float* lin2_b  = (const float*)d_in[10];
    float* out = (float*)d_out;

    // workspace layout (all 16B aligned)
    char* base = (char*)d_ws;
    unsigned char* tmp8 = (unsigned char*)base; base += (size_t)N_NODES * 512;  // 5.12 MB interleaved
    ushort* hA16   = (ushort*)base;    base += (size_t)N_TOT * HID * 2;         // 10.24 MB
    ushort* x_bf   = (ushort*)base;    base += (size_t)N_TOT * 64 * 2;          // 5.12 MB
    ushort* wt_hi  = (ushort*)base;    base += 57344 * 2;
    ushort* wt_lo  = (ushort*)base;    base += 57344 * 2;
    float*  partial= (float*)base;     base += (size_t)N_LAYERS * BS * CHUNKS * HID * 4; // 20.5 MB
    float*  partial2=(float*)base;     base += (size_t)N_LAYERS * BS * 32 * HID * 4;     // 262 KB
    float*  pooled = (float*)base;     base += N_LAYERS * BS * HID * 4;
    float*  h1     = (float*)base;     base += BS * HID_FC * 4;
    // contiguous zeroed int region: counts|cursor|csr
    int*    counts = (int*)base;       base += N_NODES * 4;
    int*    cursor = (int*)base;       base += N_NODES * 4;
    int2*   csr    = (int2*)base;      // 10000*64 int2 = 5.12 MB

    const int GE = (N_EDGES + 255) / 256;   // 625

    k_prep<<<1024, 256, 0, stream>>>(x, W1, Ws, (int4*)counts, x_bf, wt_hi, wt_lo);
    k_count<<<GE, 256, 0, stream>>>(ei, counts);
    k_fill<<<GE, 256, 0, stream>>>(ei, counts, cursor, csr);

    const int agg_grid = CHUNKS;                 // 2500
    const int mm_grid = (N_TOT + 127) / 128;     // 313

    k_mm<64><<<mm_grid, 256, 0, stream>>>(x_bf, wt_hi, wt_lo, tmp8);
    k_agg<<<agg_grid, 128, 0, stream>>>((const uint2*)tmp8, counts, csr, b1,
                                        (uint4*)hA16, partial);
    for (int l = 1; l < N_LAYERS; ++l) {
        const ushort* whi = wt_hi + 8192 + (size_t)(l - 1) * 16384;
        const ushort* wlo = wt_lo + 8192 + (size_t)(l - 1) * 16384;
        const float* bl = bconvs + (size_t)(l - 1) * HID;
        k_mm<128><<<mm_grid, 256, 0, stream>>>(hA16, whi, wlo, tmp8);
        k_agg<<<agg_grid, 128, 0, stream>>>((const uint2*)tmp8, counts, csr, bl,
                                            (uint4*)hA16,
                                            partial + (size_t)l * BS * CHUNKS * HID);
    }

    k_red1<<<N_LAYERS * BS * 32, 128, 0, stream>>>(partial, partial2);
    k_red2<<<N_LAYERS * BS, 128, 0, stream>>>(partial2, pooled);
    k_lin1<<<HID_FC / 32, 256, 0, stream>>>(pooled, lin1_w, lin1_b, h1);
    k_lin2<<<1, 512, 0, stream>>>(h1, lin2_w, lin2_b, out);
}